// Round 2
// baseline (493.527 us; speedup 1.0000x reference)
//
#include <hip/hip_runtime.h>
#include <cstdint>
#include <cstddef>

// ---------------------------------------------------------------------------
// DetCenterDense: fused conv3x3(128->64)+ReLU -> 4x conv1x1 heads (20 ch total,
// sigmoid on last 4) over [4,128,512,512] fp32, NCHW. bf16 MFMA implicit GEMM.
// R2: T14 async-STAGE pipeline (reg prefetch of next cin-chunk under MFMA),
//     native bf16 casts (v_cvt_pk_bf16_f32), (s>>1) XOR swizzle for
//     conflict-free ds_read_b128, dwordx2 staging loads.
// ---------------------------------------------------------------------------

typedef __bf16 bf16x8 __attribute__((ext_vector_type(8)));
typedef float f32x16 __attribute__((ext_vector_type(16)));
typedef float f32x2 __attribute__((ext_vector_type(2)));

// ---------------------------------------------------------------------------
// Prepass: repack w_shared [64][128][3][3] fp32 -> bf16 fragment-ordered buffer
// ws2 layout: [kappa(72)][hw(2)][och(64)][8 bf16]
//   kappa = (cin>>5)*18 + tap*2 + ((cin>>4)&1); hw=(cin>>3)&1; j=cin&7
// ---------------------------------------------------------------------------
__global__ void prep_w_kernel(const float* __restrict__ w, __bf16* __restrict__ ws2) {
    int idx = blockIdx.x * 256 + threadIdx.x;
    if (idx >= 64 * 128 * 9) return;
    int tap = idx % 9;
    int cin = (idx / 9) % 128;
    int och = idx / (9 * 128);
    int chunk = cin >> 5;
    int c32 = cin & 31;
    int ks = (c32 >> 4) & 1;
    int hw = (c32 >> 3) & 1;
    int j  = c32 & 7;
    int kappa = chunk * 18 + tap * 2 + ks;
    int dst = ((kappa * 2 + hw) * 64 + och) * 8 + j;
    ws2[dst] = (__bf16)w[idx];
}

// ---------------------------------------------------------------------------
// Main fused kernel.
// Grid: (W/128=4, H/2=256, B=4). Block: 256 threads = 4 waves.
// Block tile: 2 rows x 128 cols. Wave tile: 64 px x 64 ch (2x2 mfma 32x32x16).
// LDS feature tile: [4 rows][132 w-slots][32 cin] bf16, slot s <-> global
// w = w0 - 2 + s. Group swizzle: octet g stored at g ^ ((s>>1)&3).
// ---------------------------------------------------------------------------
__global__ __launch_bounds__(256, 2)
void det_main_kernel(const float* __restrict__ feature,
                     const __bf16* __restrict__ ws2,
                     const float* __restrict__ w_cls, const float* __restrict__ b_cls,
                     const float* __restrict__ w_box, const float* __restrict__ b_box,
                     const float* __restrict__ w_dir, const float* __restrict__ b_dir,
                     const float* __restrict__ w_scr, const float* __restrict__ b_scr,
                     float* __restrict__ out) {
    __shared__ __align__(16) unsigned short s_f[4 * 132 * 32];   // 33 KB
    __shared__ __align__(16) unsigned short s_wc[32 * 64];       // 4 KB
    __shared__ float s_bias[32];

    const int tid  = threadIdx.x;
    const int lane = tid & 63;
    const int wave = tid >> 6;
    const int l31  = lane & 31;
    const int hw   = lane >> 5;
    const int wrow = wave >> 1;
    const int wcb  = (wave & 1) * 64;
    const int bz = blockIdx.z;
    const int h0 = blockIdx.y * 2;
    const int w0 = blockIdx.x * 128;
    const size_t CH = 512 * 512;

    // staging geometry: main = (c8, pair) covering slots {2+2p, 3+2p}, rows 0..3
    const int c8 = tid >> 6;      // cin octet
    const int pr = tid & 63;      // w-pair
    // edge: threads 0..31 cover slots {0,1} (ee=0) / {130,131} (ee=1)
    const bool is_edge = tid < 32;
    const int ec8 = (tid >> 3) & 3;
    const int er  = (tid >> 1) & 3;
    const int ee  = tid & 1;

    // ---- stage 1x1-head weights (bf16, row-swizzled) + bias into LDS ----
    {
        int och = tid >> 3;
        int j8  = (tid & 7) * 8;
        float v[8];
        if (och < 20) {
            const float* src = (och < 2)  ? (w_cls + och * 64)
                             : (och < 8)  ? (w_box + (och - 2) * 64)
                             : (och < 16) ? (w_dir + (och - 8) * 64)
                                          : (w_scr + (och - 16) * 64);
            #pragma unroll
            for (int j = 0; j < 8; ++j) v[j] = src[j8 + j];
        } else {
            #pragma unroll
            for (int j = 0; j < 8; ++j) v[j] = 0.f;
        }
        bf16x8 wv;
        #pragma unroll
        for (int j = 0; j < 8; ++j) wv[j] = (__bf16)v[j];
        int off = och * 128 + ((j8 * 2) ^ ((och & 7) << 4));
        *(bf16x8*)((char*)s_wc + off) = wv;
        if (tid < 32) {
            s_bias[tid] = (tid < 2)  ? b_cls[tid]
                        : (tid < 8)  ? b_box[tid - 2]
                        : (tid < 16) ? b_dir[tid - 8]
                        : (tid < 20) ? b_scr[tid - 16] : 0.f;
        }
    }

    // ---- prefetch registers ----
    f32x2 R[4][8];   // [row][cin octet elem] main pair
    f32x2 E[8];      // edge pair (threads 0..31 only)

    const bool ewok = ee ? (w0 + 128 < 512) : (w0 - 2 >= 0);
    const int  ew   = ee ? (w0 + 128) : (w0 - 2);

    auto issue_loads = [&](int chunk) {
        const float* base = feature + (size_t)(bz * 128 + chunk * 32 + c8 * 8) * CH
                          + (w0 + 2 * pr);
        #pragma unroll
        for (int r = 0; r < 4; ++r) {
            int h = h0 - 1 + r;
            bool ok = (unsigned)h < 512u;          // block-uniform
            const float* rp = base + (size_t)h * 512;
            #pragma unroll
            for (int j = 0; j < 8; ++j) {
                f32x2 z; z[0] = 0.f; z[1] = 0.f;
                R[r][j] = ok ? *(const f32x2*)(rp + (size_t)j * CH) : z;
            }
        }
        if (is_edge) {
            int h = h0 - 1 + er;
            bool ok = ewok && ((unsigned)h < 512u);
            const float* ep = feature + (size_t)(bz * 128 + chunk * 32 + ec8 * 8) * CH
                            + (size_t)h * 512 + ew;
            #pragma unroll
            for (int j = 0; j < 8; ++j) {
                f32x2 z; z[0] = 0.f; z[1] = 0.f;
                E[j] = ok ? *(const f32x2*)(ep + (size_t)j * CH) : z;
            }
        }
    };

    auto write_phase = [&]() {
        const int s0 = 2 + 2 * pr;
        const int g  = c8 ^ (((s0 >> 1)) & 3);   // same for s0 and s0+1
        #pragma unroll
        for (int r = 0; r < 4; ++r) {
            bf16x8 a, b;
            #pragma unroll
            for (int j = 0; j < 8; ++j) {
                a[j] = (__bf16)R[r][j][0];
                b[j] = (__bf16)R[r][j][1];
            }
            *(bf16x8*)(s_f + ((r * 132 + s0) * 32 + g * 8))     = a;
            *(bf16x8*)(s_f + ((r * 132 + s0 + 1) * 32 + g * 8)) = b;
        }
        if (is_edge) {
            const int es0 = ee ? 130 : 0;
            const int eg  = ec8 ^ ((es0 >> 1) & 3);
            bf16x8 a, b;
            #pragma unroll
            for (int j = 0; j < 8; ++j) {
                a[j] = (__bf16)E[j][0];
                b[j] = (__bf16)E[j][1];
            }
            *(bf16x8*)(s_f + ((er * 132 + es0) * 32 + eg * 8))     = a;
            *(bf16x8*)(s_f + ((er * 132 + es0 + 1) * 32 + eg * 8)) = b;
        }
    };

    f32x16 zero16;
    #pragma unroll
    for (int e = 0; e < 16; ++e) zero16[e] = 0.f;
    f32x16 acc[2][2];
    acc[0][0] = zero16; acc[0][1] = zero16; acc[1][0] = zero16; acc[1][1] = zero16;

    issue_loads(0);

    for (int chunk = 0; chunk < 4; ++chunk) {
        write_phase();           // vmcnt waits on R inside
        __syncthreads();         // s_f ready for all waves
        if (chunk < 3) issue_loads(chunk + 1);   // in flight under MFMA

        #pragma unroll
        for (int tap = 0; tap < 9; ++tap) {
            const int kh = tap / 3, kw = tap % 3;
            bf16x8 B[2][2];   // [ks][nt] weights from global (L2-resident)
            #pragma unroll
            for (int ks = 0; ks < 2; ++ks) {
                #pragma unroll
                for (int nt = 0; nt < 2; ++nt) {
                    size_t bi = ((size_t)(((chunk * 18 + tap * 2 + ks) * 2 + hw) * 64
                                          + nt * 32 + l31)) * 8;
                    B[ks][nt] = *(const bf16x8*)(ws2 + bi);
                }
            }
            bf16x8 A[2][2];   // [mt][ks] feature patches from LDS
            #pragma unroll
            for (int mt = 0; mt < 2; ++mt) {
                #pragma unroll
                for (int ks = 0; ks < 2; ++ks) {
                    int fws = wcb + mt * 32 + l31 + kw + 1;
                    int g   = (ks * 2 + hw) ^ ((fws >> 1) & 3);
                    int off = ((wrow + kh) * 132 + fws) * 32 + g * 8;
                    A[mt][ks] = *(const bf16x8*)(s_f + off);
                }
            }
            #pragma unroll
            for (int mt = 0; mt < 2; ++mt) {
                #pragma unroll
                for (int nt = 0; nt < 2; ++nt) {
                    acc[mt][nt] = __builtin_amdgcn_mfma_f32_32x32x16_bf16(
                        A[mt][0], B[0][nt], acc[mt][nt], 0, 0, 0);
                    acc[mt][nt] = __builtin_amdgcn_mfma_f32_32x32x16_bf16(
                        A[mt][1], B[1][nt], acc[mt][nt], 0, 0, 0);
                }
            }
        }
        __syncthreads();         // all waves done reading s_f
    }

    // ---- ReLU -> bf16 X tile in LDS (reuse s_f), row-XOR swizzled ----
    __bf16* X = (__bf16*)s_f;
    #pragma unroll
    for (int mt = 0; mt < 2; ++mt) {
        #pragma unroll
        for (int nt = 0; nt < 2; ++nt) {
            #pragma unroll
            for (int r = 0; r < 16; ++r) {
                float v = fmaxf(acc[mt][nt][r], 0.f);
                int mrow = (r & 3) + 8 * (r >> 2) + 4 * hw;
                int pxb  = wave * 64 + mt * 32 + mrow;
                int ch   = nt * 32 + l31;
                int off  = pxb * 128 + ((ch * 2) ^ ((pxb & 7) << 4));
                *(__bf16*)((char*)X + off) = (__bf16)v;
            }
        }
    }
    // wave-local write->read: compiler orders via lgkmcnt

    // ---- stage 2: out[och(20->32)][px] = Wc @ X, K=64 ----
    f32x16 acc2[2];
    acc2[0] = zero16; acc2[1] = zero16;
    #pragma unroll
    for (int ks = 0; ks < 4; ++ks) {
        int ch0 = ks * 16 + hw * 8;
        int offA = l31 * 128 + ((ch0 * 2) ^ ((l31 & 7) << 4));
        bf16x8 a2 = *(const bf16x8*)((const char*)s_wc + offA);
        #pragma unroll
        for (int nt = 0; nt < 2; ++nt) {
            int pxb  = wave * 64 + nt * 32 + l31;
            int offB = pxb * 128 + ((ch0 * 2) ^ ((pxb & 7) << 4));
            bf16x8 b2 = *(const bf16x8*)((const char*)X + offB);
            acc2[nt] = __builtin_amdgcn_mfma_f32_32x32x16_bf16(a2, b2, acc2[nt], 0, 0, 0);
        }
    }

    // ---- epilogue: bias, sigmoid on och 16..19, coalesced stores ----
    const int h = h0 + wrow;
    #pragma unroll
    for (int nt = 0; nt < 2; ++nt) {
        int wg = w0 + wcb + nt * 32 + l31;
        #pragma unroll
        for (int r = 0; r < 16; ++r) {
            int och = (r & 3) + 8 * (r >> 2) + 4 * hw;
            if (och < 20) {
                float v = acc2[nt][r] + s_bias[och];
                if (och >= 16) v = 1.f / (1.f + __expf(-v));
                out[(((size_t)bz * 20 + och) * 512 + h) * 512 + wg] = v;
            }
        }
    }
}

extern "C" void kernel_launch(void* const* d_in, const int* in_sizes, int n_in,
                              void* d_out, int out_size, void* d_ws, size_t ws_size,
                              hipStream_t stream) {
    const float* feature  = (const float*)d_in[0];
    const float* w_shared = (const float*)d_in[1];
    const float* w_cls = (const float*)d_in[2];
    const float* b_cls = (const float*)d_in[3];
    const float* w_box = (const float*)d_in[4];
    const float* b_box = (const float*)d_in[5];
    const float* w_dir = (const float*)d_in[6];
    const float* b_dir = (const float*)d_in[7];
    const float* w_scr = (const float*)d_in[8];
    const float* b_scr = (const float*)d_in[9];
    float* out = (float*)d_out;
    __bf16* ws2 = (__bf16*)d_ws;   // 64*1152 bf16 = 147456 B

    prep_w_kernel<<<288, 256, 0, stream>>>(w_shared, ws2);

    dim3 grid(4, 256, 4);   // (W/128, H/2, B)
    det_main_kernel<<<grid, 256, 0, stream>>>(feature, ws2,
                                              w_cls, b_cls, w_box, b_box,
                                              w_dir, b_dir, w_scr, b_scr, out);
}

// Round 3
// 286.128 us; speedup vs baseline: 1.7248x; 1.7248x over previous
//
#include <hip/hip_runtime.h>
#include <cstdint>
#include <cstddef>

// ---------------------------------------------------------------------------
// DetCenterDense: fused conv3x3(128->64)+ReLU -> 4x conv1x1 heads (20 ch total,
// sigmoid on last 4) over [4,128,512,512] fp32, NCHW. bf16 MFMA implicit GEMM.
// R3: half-chunk (16-cin) double-buffered pipeline, 32-VGPR prefetch (no spill),
//     1 barrier/half-chunk, bijective XOR bank swizzle, dwordx4 staging loads.
// ---------------------------------------------------------------------------

typedef __bf16 bf16x8 __attribute__((ext_vector_type(8)));
typedef float f32x16 __attribute__((ext_vector_type(16)));
typedef float f32x4v __attribute__((ext_vector_type(4)));
typedef float f32x2v __attribute__((ext_vector_type(2)));

// LDS feature buffer: [2 bufs][4 rows][132 slots][16 cin] bf16.
// Granule = 8 bf16 (16 B) at (row, s, hw). Linear: lin = s*32 + hw*16.
// Swizzle (bijective, spreads both ds_write and ds_read uniformly):
//   byte = lin ^ ((s&1)<<4) ^ (((s>>2)&3)<<5)
//        = lin ^ ((lin>>1)&0x10) ^ ((lin>>2)&0x60)
__device__ __forceinline__ int swz(int s, int hw) {
    int lin = (s << 5) | (hw << 4);
    return lin ^ ((lin >> 1) & 0x10) ^ ((lin >> 2) & 0x60);
}

// ---------------------------------------------------------------------------
// Prepass: repack w_shared [64][128][3][3] fp32 -> bf16 fragment-ordered buffer
// ws2 layout: [kappa(72)][hw(2)][och(64)][8 bf16]
//   kappa = (cin>>5)*18 + tap*2 + ((cin>>4)&1); hw=(cin>>3)&1; j=cin&7
// ---------------------------------------------------------------------------
__global__ void prep_w_kernel(const float* __restrict__ w, __bf16* __restrict__ ws2) {
    int idx = blockIdx.x * 256 + threadIdx.x;
    if (idx >= 64 * 128 * 9) return;
    int tap = idx % 9;
    int cin = (idx / 9) % 128;
    int och = idx / (9 * 128);
    int chunk = cin >> 5;
    int c32 = cin & 31;
    int ks = (c32 >> 4) & 1;
    int hw = (c32 >> 3) & 1;
    int j  = c32 & 7;
    int kappa = chunk * 18 + tap * 2 + ks;
    int dst = ((kappa * 2 + hw) * 64 + och) * 8 + j;
    ws2[dst] = (__bf16)w[idx];
}

// ---------------------------------------------------------------------------
// Main fused kernel.
// Grid: (W/128=4, H/2=256, B=4). Block: 256 threads = 4 waves.
// Block tile: 2 rows x 128 cols. Wave tile: 64 px x 64 ch (2x2 mfma 32x32x16).
// K loop: 8 half-chunks of 16 cin, double-buffered LDS, 1 barrier each.
// ---------------------------------------------------------------------------
__global__ __launch_bounds__(256, 2)
void det_main_kernel(const float* __restrict__ feature,
                     const __bf16* __restrict__ ws2,
                     const float* __restrict__ w_cls, const float* __restrict__ b_cls,
                     const float* __restrict__ w_box, const float* __restrict__ b_box,
                     const float* __restrict__ w_dir, const float* __restrict__ b_dir,
                     const float* __restrict__ w_scr, const float* __restrict__ b_scr,
                     float* __restrict__ out) {
    __shared__ __align__(16) unsigned short s_f[16896];   // 2 x 16896 B = 33792 B
    __shared__ __align__(16) unsigned short s_wc[32 * 64]; // 4 KB
    __shared__ float s_bias[32];

    const int tid  = threadIdx.x;
    const int lane = tid & 63;
    const int wave = tid >> 6;
    const int l31  = lane & 31;
    const int hw   = lane >> 5;
    const int wrow = wave >> 1;
    const int wcb  = (wave & 1) * 64;
    const int bz = blockIdx.z;
    const int h0 = blockIdx.y * 2;
    const int w0 = blockIdx.x * 128;
    const size_t CH = 512 * 512;

    // ---- staging roles ----
    // main: all 256 threads; thread covers (hw octet, s-quad, row):
    //   8 cin x 4 slots x 1 row = 32 floats = 8 dwordx4 loads, 4 b128 LDS writes
    const int m_hw  = tid & 1;
    const int m_q   = (tid >> 1) & 31;      // s-quad: slots 2+4q .. 5+4q
    const int m_row = tid >> 6;             // staged row 0..3 (== wave)
    const int m_h   = h0 - 1 + m_row;
    const bool m_ok = (unsigned)m_h < 512u;
    const float* m_base = feature + (size_t)(bz * 128 + m_hw * 8) * CH
                        + (size_t)(m_ok ? m_h : 0) * 512 + (w0 + 4 * m_q);

    // edge: threads 0..127 additionally cover slots {0,1} / {130,131}:
    //   1 dwordx2 load, 2 b16 LDS writes
    const bool e_on = tid < 128;
    const int e_ee  = (tid >> 6) & 1;
    const int e_row = (tid >> 4) & 3;
    const int e_cin = tid & 15;
    const int e_h   = h0 - 1 + e_row;
    const int e_w   = e_ee ? (w0 + 128) : (w0 - 2);
    const bool e_ok = e_on && ((unsigned)e_h < 512u) && ((unsigned)e_w < 511u);
    const float* e_base = feature + (size_t)(bz * 128 + e_cin) * CH
                        + (size_t)(e_ok ? e_h : 0) * 512 + (e_ok ? e_w : 0);

    // ---- stage 1x1-head weights (bf16, row-swizzled) + bias into LDS ----
    {
        int och = tid >> 3;
        int j8  = (tid & 7) * 8;
        float v[8];
        if (och < 20) {
            const float* src = (och < 2)  ? (w_cls + och * 64)
                             : (och < 8)  ? (w_box + (och - 2) * 64)
                             : (och < 16) ? (w_dir + (och - 8) * 64)
                                          : (w_scr + (och - 16) * 64);
            #pragma unroll
            for (int j = 0; j < 8; ++j) v[j] = src[j8 + j];
        } else {
            #pragma unroll
            for (int j = 0; j < 8; ++j) v[j] = 0.f;
        }
        bf16x8 wv;
        #pragma unroll
        for (int j = 0; j < 8; ++j) wv[j] = (__bf16)v[j];
        int off = och * 128 + ((j8 * 2) ^ ((och & 7) << 4));
        *(bf16x8*)((char*)s_wc + off) = wv;
        if (tid < 32) {
            s_bias[tid] = (tid < 2)  ? b_cls[tid]
                        : (tid < 8)  ? b_box[tid - 2]
                        : (tid < 16) ? b_dir[tid - 8]
                        : (tid < 20) ? b_scr[tid - 16] : 0.f;
        }
    }

    f32x4v R[8];      // prefetch: 8 cin x 4 slots (32 VGPR)
    f32x2v E;         // edge prefetch (2 VGPR, threads 0..127)

    f32x4v zero4; zero4[0] = 0.f; zero4[1] = 0.f; zero4[2] = 0.f; zero4[3] = 0.f;
    f32x2v zero2; zero2[0] = 0.f; zero2[1] = 0.f;

    // issue global loads for half-chunk hc (16 cin planes starting hc*16)
    auto issue_loads = [&](int hc) {
        const float* p = m_base + (size_t)(hc * 16) * CH;
        #pragma unroll
        for (int j = 0; j < 8; ++j) {
            f32x4v v = *(const f32x4v*)(p + (size_t)j * CH);
            R[j] = m_ok ? v : zero4;
        }
        if (e_on) {
            f32x2v v = *(const f32x2v*)(e_base + (size_t)(hc * 16) * CH);
            E = e_ok ? v : zero2;
        }
    };

    // convert + write prefetched data into LDS buffer (hc&1)
    auto write_phase = [&](int hc) {
        char* buf = (char*)s_f + (hc & 1) * 16896;
        #pragma unroll
        for (int k = 0; k < 4; ++k) {
            bf16x8 g;
            #pragma unroll
            for (int j = 0; j < 8; ++j) g[j] = (__bf16)R[j][k];
            int s = 2 + 4 * m_q + k;
            *(bf16x8*)(buf + m_row * 4224 + swz(s, m_hw)) = g;
        }
        if (e_on) {
            char* b2 = buf + e_row * 4224 + (e_cin & 7) * 2;
            int s0 = e_ee ? 130 : 0;
            *(__bf16*)(b2 + swz(s0,     e_cin >> 3)) = (__bf16)E[0];
            *(__bf16*)(b2 + swz(s0 + 1, e_cin >> 3)) = (__bf16)E[1];
        }
    };

    f32x16 zero16;
    #pragma unroll
    for (int e = 0; e < 16; ++e) zero16[e] = 0.f;
    f32x16 acc[2][2];
    acc[0][0] = zero16; acc[0][1] = zero16; acc[1][0] = zero16; acc[1][1] = zero16;

    issue_loads(0);

    for (int h = 0; h < 8; ++h) {
        write_phase(h);                     // waits vmcnt on R, converts, ds_write
        __syncthreads();                    // buf[h&1] ready; buf[(h+1)&1] free
        if (h < 7) issue_loads(h + 1);      // in flight under MFMA phase

        const char* buf = (const char*)s_f + (h & 1) * 16896;
        #pragma unroll
        for (int tap = 0; tap < 9; ++tap) {
            const int kh = tap / 3, kw = tap % 3;
            bf16x8 Bf[2];
            #pragma unroll
            for (int nt = 0; nt < 2; ++nt) {
                size_t bi = ((size_t)(((((h >> 1) * 18 + tap * 2 + (h & 1))) * 2 + hw) * 64
                                      + nt * 32 + l31)) * 8;
                Bf[nt] = *(const bf16x8*)(ws2 + bi);
            }
            bf16x8 Af[2];
            #pragma unroll
            for (int mt = 0; mt < 2; ++mt) {
                int s = wcb + mt * 32 + l31 + kw + 1;
                Af[mt] = *(const bf16x8*)(buf + (wrow + kh) * 4224 + swz(s, hw));
            }
            #pragma unroll
            for (int mt = 0; mt < 2; ++mt) {
                #pragma unroll
                for (int nt = 0; nt < 2; ++nt) {
                    acc[mt][nt] = __builtin_amdgcn_mfma_f32_32x32x16_bf16(
                        Af[mt], Bf[nt], acc[mt][nt], 0, 0, 0);
                }
            }
        }
    }

    // ---- ReLU -> bf16 X tile in LDS (reuse s_f), row-XOR swizzled ----
    __syncthreads();   // all waves done reading s_f buffers
    __bf16* X = (__bf16*)s_f;   // [256 px][64 ch] bf16 = 32 KB (fits in 33.8 KB)
    #pragma unroll
    for (int mt = 0; mt < 2; ++mt) {
        #pragma unroll
        for (int nt = 0; nt < 2; ++nt) {
            #pragma unroll
            for (int r = 0; r < 16; ++r) {
                float v = fmaxf(acc[mt][nt][r], 0.f);
                int mrow = (r & 3) + 8 * (r >> 2) + 4 * hw;
                int pxb  = wave * 64 + mt * 32 + mrow;
                int ch   = nt * 32 + l31;
                int off  = pxb * 128 + ((ch * 2) ^ ((pxb & 7) << 4));
                *(__bf16*)((char*)X + off) = (__bf16)v;
            }
        }
    }
    // wave-local write->read: compiler orders via lgkmcnt

    // ---- stage 2: out[och(20->32)][px] = Wc @ X, K=64 ----
    f32x16 acc2[2];
    acc2[0] = zero16; acc2[1] = zero16;
    #pragma unroll
    for (int ks = 0; ks < 4; ++ks) {
        int ch0 = ks * 16 + hw * 8;
        int offA = l31 * 128 + ((ch0 * 2) ^ ((l31 & 7) << 4));
        bf16x8 a2 = *(const bf16x8*)((const char*)s_wc + offA);
        #pragma unroll
        for (int nt = 0; nt < 2; ++nt) {
            int pxb  = wave * 64 + nt * 32 + l31;
            int offB = pxb * 128 + ((ch0 * 2) ^ ((pxb & 7) << 4));
            bf16x8 b2 = *(const bf16x8*)((const char*)X + offB);
            acc2[nt] = __builtin_amdgcn_mfma_f32_32x32x16_bf16(a2, b2, acc2[nt], 0, 0, 0);
        }
    }

    // ---- epilogue: bias, sigmoid on och 16..19, coalesced stores ----
    const int h = h0 + wrow;
    #pragma unroll
    for (int nt = 0; nt < 2; ++nt) {
        int wg = w0 + wcb + nt * 32 + l31;
        #pragma unroll
        for (int r = 0; r < 16; ++r) {
            int och = (r & 3) + 8 * (r >> 2) + 4 * hw;
            if (och < 20) {
                float v = acc2[nt][r] + s_bias[och];
                if (och >= 16) v = 1.f / (1.f + __expf(-v));
                out[(((size_t)bz * 20 + och) * 512 + h) * 512 + wg] = v;
            }
        }
    }
}

extern "C" void kernel_launch(void* const* d_in, const int* in_sizes, int n_in,
                              void* d_out, int out_size, void* d_ws, size_t ws_size,
                              hipStream_t stream) {
    const float* feature  = (const float*)d_in[0];
    const float* w_shared = (const float*)d_in[1];
    const float* w_cls = (const float*)d_in[2];
    const float* b_cls = (const float*)d_in[3];
    const float* w_box = (const float*)d_in[4];
    const float* b_box = (const float*)d_in[5];
    const float* w_dir = (const float*)d_in[6];
    const float* b_dir = (const float*)d_in[7];
    const float* w_scr = (const float*)d_in[8];
    const float* b_scr = (const float*)d_in[9];
    float* out = (float*)d_out;
    __bf16* ws2 = (__bf16*)d_ws;   // 64*1152 bf16 = 147456 B

    prep_w_kernel<<<288, 256, 0, stream>>>(w_shared, ws2);

    dim3 grid(4, 256, 4);   // (W/128, H/2, B)
    det_main_kernel<<<grid, 256, 0, stream>>>(feature, ws2,
                                              w_cls, b_cls, w_box, b_box,
                                              w_dir, b_dir, w_scr, b_scr, out);
}

// Round 4
// 261.641 us; speedup vs baseline: 1.8863x; 1.0936x over previous
//
#include <hip/hip_runtime.h>
#include <cstdint>
#include <cstddef>

// ---------------------------------------------------------------------------
// DetCenterDense: fused conv3x3(128->64)+ReLU -> 4x conv1x1 heads (20 ch total,
// sigmoid on last 4) over [4,128,512,512] fp32, NCHW. bf16 MFMA implicit GEMM.
// R4: counted-vmcnt schedule (T3/T4): B-weights staged to LDS via
//     global_load_lds (1 iter ahead), A staged via 2-deep register prefetch
//     (Ra/Rb) with raw s_barrier + s_waitcnt vmcnt(9) so A(h+2) stays in
//     flight across the barrier. XCD-aware block swizzle for halo L2 reuse.
//     T5 setprio around MFMA quads.
// ---------------------------------------------------------------------------

typedef __bf16 bf16x8 __attribute__((ext_vector_type(8)));
typedef float f32x16 __attribute__((ext_vector_type(16)));
typedef float f32x4v __attribute__((ext_vector_type(4)));
typedef float f32x2v __attribute__((ext_vector_type(2)));

// A-tile LDS swizzle (validated in R3): granule 16B at (row, s, hw):
//   lin = s*32 + hw*16 ; byte = lin ^ ((lin>>1)&0x10) ^ ((lin>>2)&0x60)
__device__ __forceinline__ int swz(int s, int hw) {
    int lin = (s << 5) | (hw << 4);
    return lin ^ ((lin >> 1) & 0x10) ^ ((lin >> 2) & 0x60);
}

// ---------------------------------------------------------------------------
// Prepass: repack w_shared [64][128][3][3] fp32 -> bf16, per-half-chunk
// contiguous so the main kernel can global_load_lds it linearly:
// ws3 layout: [hc(8)][tap(9)][hw(2)][och(64)][8 bf16]   (18432 B per hc)
//   hc = cin>>4 ; hw = (cin>>3)&1 ; j = cin&7
// ---------------------------------------------------------------------------
__global__ void prep_w_kernel(const float* __restrict__ w, __bf16* __restrict__ ws3) {
    int idx = blockIdx.x * 256 + threadIdx.x;
    if (idx >= 64 * 128 * 9) return;
    int tap = idx % 9;
    int cin = (idx / 9) % 128;
    int och = idx / (9 * 128);
    int hc = cin >> 4;
    int hw = (cin >> 3) & 1;
    int j  = cin & 7;
    int dst = (((hc * 9 + tap) * 2 + hw) * 64 + och) * 8 + j;
    ws3[dst] = (__bf16)w[idx];
}

// LDS memory map (bytes):
//   A0 @ 0      [16896]   A1 @ 16896 [16896]    (A tile: [4 rows][132 s][16 cin] bf16, swizzled)
//   B0 @ 33792  [18432]   B1 @ 52224 [18432]    (B: [tap 9][hw 2][och 64][8 bf16], linear)
//   wc @ 70656  [4096]    bias @ 74752 [128]
#define A_OFF(p)  ((p) ? 16896 : 0)
#define B_OFF(p)  (33792 + ((p) ? 18432 : 0))

__global__ __launch_bounds__(256, 2)
void det_main_kernel(const float* __restrict__ feature,
                     const __bf16* __restrict__ ws3,
                     const float* __restrict__ w_cls, const float* __restrict__ b_cls,
                     const float* __restrict__ w_box, const float* __restrict__ b_box,
                     const float* __restrict__ w_dir, const float* __restrict__ b_dir,
                     const float* __restrict__ w_scr, const float* __restrict__ b_scr,
                     float* __restrict__ out) {
    __shared__ __align__(1024) char s_all[74880];

    const int tid  = threadIdx.x;
    const int lane = tid & 63;
    const int wave = tid >> 6;
    const int l31  = lane & 31;
    const int hw   = lane >> 5;
    const int wrow = wave >> 1;
    const int wcb  = (wave & 1) * 64;

    // ---- XCD-aware decode: 4096 blocks -> 8 chunks of 512; within a chunk
    // vertical neighbors (sharing halo rows) are schedule-adjacent.
    const int bid = blockIdx.x;
    const int wg  = (bid & 7) * 512 + (bid >> 3);
    const int ck  = wg >> 9;            // 0..7: (z, x-pair)
    const int bz  = ck >> 1;
    const int rem = wg & 511;
    const int h0  = (rem >> 1) * 2;
    const int w0  = ((ck & 1) * 2 + (rem & 1)) * 128;
    const size_t CH = 512 * 512;

    // ---- staging roles ----
    // main: thread covers (cin octet m_hw, s-quad m_q, row m_row): 8 dwordx4
    const int m_hw  = tid & 1;
    const int m_q   = (tid >> 1) & 31;
    const int m_row = tid >> 6;
    const int m_h   = h0 - 1 + m_row;
    const bool m_ok = (unsigned)m_h < 512u;
    const float* m_base = feature + (size_t)(bz * 128 + m_hw * 8) * CH
                        + (size_t)(m_ok ? m_h : 0) * 512 + (w0 + 4 * m_q);

    // edge: even lanes of EVERY wave (uniform per-wave vmem count): 1 dwordx2
    const bool e_on = (tid & 1) == 0;
    const int e_idx = tid >> 1;              // 0..127 across waves
    const int e_ee  = (e_idx >> 6) & 1;
    const int e_row = (e_idx >> 4) & 3;
    const int e_cin = e_idx & 15;
    const int e_h   = h0 - 1 + e_row;
    const int e_w   = e_ee ? (w0 + 128) : (w0 - 2);
    const bool e_ok = ((unsigned)e_h < 512u) && ((unsigned)e_w < 511u);
    const float* e_base = feature + (size_t)(bz * 128 + e_cin) * CH
                        + (size_t)(e_ok ? e_h : 0) * 512 + (e_ok ? e_w : 0);

    // ---- stage 1x1-head weights (bf16, row-swizzled) + bias into LDS ----
    {
        char* s_wc = s_all + 70656;
        float* s_bias = (float*)(s_all + 74752);
        int och = tid >> 3;
        int j8  = (tid & 7) * 8;
        float v[8];
        if (och < 20) {
            const float* src = (och < 2)  ? (w_cls + och * 64)
                             : (och < 8)  ? (w_box + (och - 2) * 64)
                             : (och < 16) ? (w_dir + (och - 8) * 64)
                                          : (w_scr + (och - 16) * 64);
            #pragma unroll
            for (int j = 0; j < 8; ++j) v[j] = src[j8 + j];
        } else {
            #pragma unroll
            for (int j = 0; j < 8; ++j) v[j] = 0.f;
        }
        bf16x8 wv;
        #pragma unroll
        for (int j = 0; j < 8; ++j) wv[j] = (__bf16)v[j];
        *(bf16x8*)(s_wc + och * 128 + ((j8 * 2) ^ ((och & 7) << 4))) = wv;
        if (tid < 32) {
            s_bias[tid] = (tid < 2)  ? b_cls[tid]
                        : (tid < 8)  ? b_box[tid - 2]
                        : (tid < 16) ? b_dir[tid - 8]
                        : (tid < 20) ? b_scr[tid - 16] : 0.f;
        }
    }

    f32x4v Ra[8], Rb[8];
    f32x2v Ea, Eb;

    // issue A-loads for half-chunk hc into (R,E). ALWAYS 9 vmem per wave
    // (8 main + 1 edge), unconditional, clamped addresses (zeroing at write).
    auto issueA = [&](int hc, f32x4v (&R)[8], f32x2v& E) {
        const float* p = m_base + (size_t)(hc * 16) * CH;
        #pragma unroll
        for (int j = 0; j < 8; ++j) R[j] = *(const f32x4v*)(p + (size_t)j * CH);
        if (e_on) E = *(const f32x2v*)(e_base + (size_t)(hc * 16) * CH);
    };

    // convert + ds_write (R,E) into A-buf[hc&1]; zero OOB here (no vmem).
    auto writeA = [&](int hc, f32x4v (&R)[8], f32x2v& E) {
        char* ab = s_all + A_OFF(hc & 1);
        #pragma unroll
        for (int k = 0; k < 4; ++k) {
            bf16x8 g;
            #pragma unroll
            for (int j = 0; j < 8; ++j) g[j] = (__bf16)(m_ok ? R[j][k] : 0.f);
            int s = 2 + 4 * m_q + k;
            *(bf16x8*)(ab + m_row * 4224 + swz(s, m_hw)) = g;
        }
        if (e_on) {
            char* b2 = ab + e_row * 4224 + (e_cin & 7) * 2;
            int s0 = e_ee ? 130 : 0;
            *(__bf16*)(b2 + swz(s0,     e_cin >> 3)) = (__bf16)(e_ok ? E[0] : 0.f);
            *(__bf16*)(b2 + swz(s0 + 1, e_cin >> 3)) = (__bf16)(e_ok ? E[1] : 0.f);
        }
    };

    // async global->LDS copy of half-chunk hc's weights (1152 granules of 16B)
    // waves 0,1: 5 instrs; waves 2,3: 4 (vmcnt handled: we always wait past B).
    auto issueB = [&](int hc) {
        char* bb = s_all + B_OFF(hc & 1);
        const char* src = (const char*)ws3 + hc * 18432;
        #pragma unroll
        for (int i = 0; i < 4; ++i) {
            int g0 = i * 256 + wave * 64;
            __builtin_amdgcn_global_load_lds(
                (const __attribute__((address_space(1))) void*)(src + (size_t)(g0 + lane) * 16),
                (__attribute__((address_space(3))) void*)(bb + g0 * 16), 16, 0, 0);
        }
        if (wave < 2) {
            int g0 = 1024 + wave * 64;
            __builtin_amdgcn_global_load_lds(
                (const __attribute__((address_space(1))) void*)(src + (size_t)(g0 + lane) * 16),
                (__attribute__((address_space(3))) void*)(bb + g0 * 16), 16, 0, 0);
        }
    };

    f32x16 zero16;
    #pragma unroll
    for (int e = 0; e < 16; ++e) zero16[e] = 0.f;
    f32x16 acc[2][2];
    acc[0][0] = zero16; acc[0][1] = zero16; acc[1][0] = zero16; acc[1][1] = zero16;

    auto mfma_phase = [&](int hc) {
        const char* ab = s_all + A_OFF(hc & 1);
        const char* bb = s_all + B_OFF(hc & 1);
        #pragma unroll
        for (int tap = 0; tap < 9; ++tap) {
            const int kh = tap / 3, kw = tap % 3;
            bf16x8 Bf0 = *(const bf16x8*)(bb + (size_t)((tap * 2 + hw) * 64 +      l31) * 16);
            bf16x8 Bf1 = *(const bf16x8*)(bb + (size_t)((tap * 2 + hw) * 64 + 32 + l31) * 16);
            bf16x8 Af0 = *(const bf16x8*)(ab + (wrow + kh) * 4224 + swz(wcb +      l31 + kw + 1, hw));
            bf16x8 Af1 = *(const bf16x8*)(ab + (wrow + kh) * 4224 + swz(wcb + 32 + l31 + kw + 1, hw));
            __builtin_amdgcn_s_setprio(1);
            acc[0][0] = __builtin_amdgcn_mfma_f32_32x32x16_bf16(Af0, Bf0, acc[0][0], 0, 0, 0);
            acc[0][1] = __builtin_amdgcn_mfma_f32_32x32x16_bf16(Af0, Bf1, acc[0][1], 0, 0, 0);
            acc[1][0] = __builtin_amdgcn_mfma_f32_32x32x16_bf16(Af1, Bf0, acc[1][0], 0, 0, 0);
            acc[1][1] = __builtin_amdgcn_mfma_f32_32x32x16_bf16(Af1, Bf1, acc[1][1], 0, 0, 0);
            __builtin_amdgcn_s_setprio(0);
        }
    };

    // ---- prologue ----
    issueA(0, Ra, Ea);
    issueB(0);
    issueA(1, Rb, Eb);
    __builtin_amdgcn_sched_barrier(0);
    writeA(0, Ra, Ea);                 // reg-dep wait drains A(0) only
    asm volatile("s_waitcnt vmcnt(9) lgkmcnt(0)" ::: "memory");  // B(0) done; A(1) in flight
    __builtin_amdgcn_s_barrier();
    __builtin_amdgcn_sched_barrier(0);

    // ---- main loop: 8 half-chunks of 16 cin ----
    #pragma unroll 1
    for (int h = 0; h < 7; ++h) {
        issueB(h + 1);                                   // into Bbuf[(h+1)&1]
        if (h < 6) {                                     // A(h+2) -> set[h&1]
            if (h & 1) issueA(h + 2, Rb, Eb); else issueA(h + 2, Ra, Ea);
        }
        __builtin_amdgcn_sched_barrier(0);
        mfma_phase(h);
        __builtin_amdgcn_sched_barrier(0);
        if (h & 1) writeA(h + 1, Ra, Ea); else writeA(h + 1, Rb, Eb);  // set[(h+1)&1]
        if (h < 6) {
            // wait B(h+1) complete; leave A(h+2)'s 9 loads in flight
            asm volatile("s_waitcnt vmcnt(9) lgkmcnt(0)" ::: "memory");
        } else {
            asm volatile("s_waitcnt vmcnt(0) lgkmcnt(0)" ::: "memory");
        }
        __builtin_amdgcn_s_barrier();
        __builtin_amdgcn_sched_barrier(0);
    }
    mfma_phase(7);

    // ---- ReLU -> bf16 X tile in LDS (reuse A region), row-XOR swizzled ----
    __syncthreads();   // nothing outstanding; full drain fine
    __bf16* X = (__bf16*)s_all;   // [256 px][64 ch] = 32 KB
    #pragma unroll
    for (int mt = 0; mt < 2; ++mt) {
        #pragma unroll
        for (int nt = 0; nt < 2; ++nt) {
            #pragma unroll
            for (int r = 0; r < 16; ++r) {
                float v = fmaxf(acc[mt][nt][r], 0.f);
                int mrow = (r & 3) + 8 * (r >> 2) + 4 * hw;
                int pxb  = wave * 64 + mt * 32 + mrow;
                int ch   = nt * 32 + l31;
                int off  = pxb * 128 + ((ch * 2) ^ ((pxb & 7) << 4));
                *(__bf16*)((char*)X + off) = (__bf16)v;
            }
        }
    }
    // wave-local write->read: compiler orders via lgkmcnt

    // ---- stage 2: out[och(20->32)][px] = Wc @ X, K=64 ----
    const char* s_wc = s_all + 70656;
    const float* s_bias = (const float*)(s_all + 74752);
    f32x16 acc2[2];
    acc2[0] = zero16; acc2[1] = zero16;
    #pragma unroll
    for (int ks = 0; ks < 4; ++ks) {
        int ch0 = ks * 16 + hw * 8;
        int offA = l31 * 128 + ((ch0 * 2) ^ ((l31 & 7) << 4));
        bf16x8 a2 = *(const bf16x8*)(s_wc + offA);
        #pragma unroll
        for (int nt = 0; nt < 2; ++nt) {
            int pxb  = wave * 64 + nt * 32 + l31;
            int offB = pxb * 128 + ((ch0 * 2) ^ ((pxb & 7) << 4));
            bf16x8 b2 = *(const bf16x8*)((const char*)X + offB);
            acc2[nt] = __builtin_amdgcn_mfma_f32_32x32x16_bf16(a2, b2, acc2[nt], 0, 0, 0);
        }
    }

    // ---- epilogue: bias, sigmoid on och 16..19, coalesced stores ----
    const int h = h0 + wrow;
    #pragma unroll
    for (int nt = 0; nt < 2; ++nt) {
        int wg2 = w0 + wcb + nt * 32 + l31;
        #pragma unroll
        for (int r = 0; r < 16; ++r) {
            int och = (r & 3) + 8 * (r >> 2) + 4 * hw;
            if (och < 20) {
                float v = acc2[nt][r] + s_bias[och];
                if (och >= 16) v = 1.f / (1.f + __expf(-v));
                out[(((size_t)bz * 20 + och) * 512 + h) * 512 + wg2] = v;
            }
        }
    }
}

extern "C" void kernel_launch(void* const* d_in, const int* in_sizes, int n_in,
                              void* d_out, int out_size, void* d_ws, size_t ws_size,
                              hipStream_t stream) {
    const float* feature  = (const float*)d_in[0];
    const float* w_shared = (const float*)d_in[1];
    const float* w_cls = (const float*)d_in[2];
    const float* b_cls = (const float*)d_in[3];
    const float* w_box = (const float*)d_in[4];
    const float* b_box = (const float*)d_in[5];
    const float* w_dir = (const float*)d_in[6];
    const float* b_dir = (const float*)d_in[7];
    const float* w_scr = (const float*)d_in[8];
    const float* b_scr = (const float*)d_in[9];
    float* out = (float*)d_out;
    __bf16* ws3 = (__bf16*)d_ws;   // 8 * 18432 B = 147456 B

    prep_w_kernel<<<288, 256, 0, stream>>>(w_shared, ws3);

    det_main_kernel<<<4096, 256, 0, stream>>>(feature, ws3,
                                              w_cls, b_cls, w_box, b_box,
                                              w_dir, b_dir, w_scr, b_scr, out);
}